// Round 3
// baseline (3791.657 us; speedup 1.0000x reference)
//
#include <hip/hip_runtime.h>

// FSRCNN fully fused, one block (1024 thr) per image, 1 px/thread. Round 3:
//  - TB=1024 -> 16 waves/CU (2x occupancy vs round 2).
//  - All-fp32 (fp16 H removed). Tail accumulates over d in 8-channel fp32
//    chunks staged in the dead A region.
//  - All ds_read are b32 with lane=col -> every bank once per row, 2 rows/wave
//    at odd/near-odd bank shift -> <=2-way (free).
//  - Weights/biases/alphas read from global with wave-uniform indices -> s_load.

#define TB 1024
#define X_OFF 0        // 3*36*36 = 3888 floats (padded input, pad=2)
#define A_OFF 3888     // 12*34*34 = 13872 floats (padded, pad=1)
#define B_OFF 17760    // 12*34*34
#define LDS_FLOATS 31632
#define LDS_BYTES (LDS_FLOATS * 4)   // 126528 B
// H chunk buffer: 8 ch x [36][37] f32 = 10656 floats, overlays A (dead after b3)
#define HC_OFF A_OFF
#define HCH   1332     // 36*37 per channel
#define HSTR  37

__global__ void __launch_bounds__(TB, 4)
fsrcnn_fused(const float* __restrict__ x,
             const float* __restrict__ head_w, const float* __restrict__ head_b, const float* __restrict__ head_a,
             const float* __restrict__ b0_w, const float* __restrict__ b0_b, const float* __restrict__ b0_a,
             const float* __restrict__ b1_w, const float* __restrict__ b1_b,
             const float* __restrict__ b2_w, const float* __restrict__ b2_b,
             const float* __restrict__ b3_w, const float* __restrict__ b3_b,
             const float* __restrict__ b4_w, const float* __restrict__ b4_b,
             const float* __restrict__ b5_a,
             const float* __restrict__ b6_w, const float* __restrict__ b6_b, const float* __restrict__ b6_a,
             const float* __restrict__ tail_w, const float* __restrict__ tail_b,
             float* __restrict__ out)
{
    extern __shared__ float lds[];
    const int tid = threadIdx.x;
    const int img = blockIdx.x;
    const int y   = tid >> 5;      // 0..31
    const int xp  = tid & 31;      // 0..31

    // ---------------- stage padded x (3x36x36), zero A+B ----------------
    {
        const float* xg = x + img * 3072;
        for (int i = tid; i < 3888; i += TB) {
            const int c = i / 1296;
            const int rem = i - c * 1296;
            const int r = rem / 36;
            const int cl = rem - r * 36;
            const int iy = r - 2, ix = cl - 2;
            float v = 0.f;
            if ((unsigned)iy < 32u && (unsigned)ix < 32u)
                v = xg[(c << 10) + (iy << 5) + ix];
            lds[X_OFF + i] = v;
        }
        float4* ab = reinterpret_cast<float4*>(&lds[A_OFF]);
        const float4 z4 = make_float4(0.f, 0.f, 0.f, 0.f);
        for (int i = tid; i < 6936; i += TB) ab[i] = z4;   // zero A and B
    }
    __syncthreads();

    // ---------------- head 5x5 3->56 + prelu + b0 1x1 56->12 + prelu -> A ----------------
    float accS[12];
    #pragma unroll
    for (int s = 0; s < 12; s++) accS[s] = b0_b[s];
    for (int d0 = 0; d0 < 56; d0 += 8) {
        float ah[8];
        #pragma unroll
        for (int dd = 0; dd < 8; dd++) ah[dd] = head_b[d0 + dd];
        #pragma unroll
        for (int ci = 0; ci < 3; ci++) {
            #pragma unroll
            for (int ky = 0; ky < 5; ky++) {
                const float* xr = &lds[X_OFF + ci * 1296 + (y + ky) * 36 + xp];
                float xv[5];
                #pragma unroll
                for (int t = 0; t < 5; t++) xv[t] = xr[t];
                #pragma unroll
                for (int dd = 0; dd < 8; dd++) {
                    const float* wr = &head_w[((d0 + dd) * 3 + ci) * 25 + ky * 5];
                    #pragma unroll
                    for (int kx = 0; kx < 5; kx++)
                        ah[dd] = fmaf(xv[kx], wr[kx], ah[dd]);   // wr uniform -> s_load
                }
            }
        }
        #pragma unroll
        for (int dd = 0; dd < 8; dd++) {
            const float al = head_a[d0 + dd];
            float v = ah[dd];
            v = (v >= 0.f) ? v : al * v;
            #pragma unroll
            for (int s = 0; s < 12; s++)
                accS[s] = fmaf(b0_w[s * 56 + d0 + dd], v, accS[s]);
        }
    }
    #pragma unroll
    for (int s = 0; s < 12; s++) {
        const float al = b0_a[s];
        float v = accS[s];
        v = (v >= 0.f) ? v : al * v;
        lds[A_OFF + s * 1156 + (y + 1) * 34 + xp + 1] = v;
    }
    __syncthreads();

    // ---------------- b1..b3: 3x3 12->12 pad1, LDS->LDS ----------------
    auto conv3 = [&](int pofs, int qofs, const float* __restrict__ w, const float* __restrict__ bias) {
        float acc[12];
        #pragma unroll
        for (int c = 0; c < 12; c++) acc[c] = bias[c];
        for (int e = 0; e < 12; e++) {
            #pragma unroll
            for (int ky = 0; ky < 3; ky++) {
                const float* pr = &lds[pofs + e * 1156 + (y + ky) * 34 + xp];
                float xv[3];
                xv[0] = pr[0]; xv[1] = pr[1]; xv[2] = pr[2];
                #pragma unroll
                for (int c = 0; c < 12; c++) {
                    const float* wr = &w[(c * 12 + e) * 9 + ky * 3];
                    #pragma unroll
                    for (int kx = 0; kx < 3; kx++)
                        acc[c] = fmaf(xv[kx], wr[kx], acc[c]);
                }
            }
        }
        #pragma unroll
        for (int c = 0; c < 12; c++)
            lds[qofs + c * 1156 + (y + 1) * 34 + xp + 1] = acc[c];
        __syncthreads();
    };
    conv3(A_OFF, B_OFF, b1_w, b1_b);
    conv3(B_OFF, A_OFF, b2_w, b2_b);
    conv3(A_OFF, B_OFF, b3_w, b3_b);

    // ---------------- b4: 3x3 + prelu(b5_a) -> registers g; zero H chunk buf ----------------
    float g[12];
    #pragma unroll
    for (int c = 0; c < 12; c++) g[c] = b4_b[c];
    for (int e = 0; e < 12; e++) {
        #pragma unroll
        for (int ky = 0; ky < 3; ky++) {
            const float* pr = &lds[B_OFF + e * 1156 + (y + ky) * 34 + xp];
            float xv[3];
            xv[0] = pr[0]; xv[1] = pr[1]; xv[2] = pr[2];
            #pragma unroll
            for (int c = 0; c < 12; c++) {
                const float* wr = &b4_w[(c * 12 + e) * 9 + ky * 3];
                #pragma unroll
                for (int kx = 0; kx < 3; kx++)
                    g[c] = fmaf(xv[kx], wr[kx], g[c]);
            }
        }
    }
    #pragma unroll
    for (int c = 0; c < 12; c++) {
        const float al = b5_a[c];
        const float v = g[c];
        g[c] = (v >= 0.f) ? v : al * v;
    }
    // zero the H chunk buffer (A region is dead: last read was conv3#3)
    {
        float4* hb = reinterpret_cast<float4*>(&lds[HC_OFF]);
        const float4 z4 = make_float4(0.f, 0.f, 0.f, 0.f);
        for (int i = tid; i < 2664; i += TB) hb[i] = z4;
    }
    __syncthreads();

    // ---------------- b6 (1x1 12->56 + prelu) chunked + tail 9x9 s2 convT ----------------
    float acc[3][4];   // [c][ry*2+rx] -> out (2y+ry, 2xp+rx)
    #pragma unroll
    for (int c = 0; c < 3; c++) {
        const float tb = tail_b[c];
        #pragma unroll
        for (int q = 0; q < 4; q++) acc[c][q] = tb;
    }
    for (int d0 = 0; d0 < 56; d0 += 8) {
        // stage 8 channels of H (fp32) into chunk buffer
        #pragma unroll
        for (int dd = 0; dd < 8; dd++) {
            const int d = d0 + dd;
            float v = b6_b[d];
            #pragma unroll
            for (int s = 0; s < 12; s++)
                v = fmaf(b6_w[d * 12 + s], g[s], v);
            const float al = b6_a[d];
            v = (v >= 0.f) ? v : al * v;
            lds[HC_OFF + dd * HCH + (y + 2) * HSTR + xp + 2] = v;
        }
        __syncthreads();
        // accumulate tail contribution of these 8 channels
        #pragma unroll
        for (int dd = 0; dd < 8; dd++) {
            const float* hb = &lds[HC_OFF + dd * HCH];
            const float* wb = &tail_w[(d0 + dd) * 243];   // [c][ky][kx], c stride 81
            #pragma unroll
            for (int j = 0; j < 5; j++) {                 // padded row y+j, m = 4-j
                const float* pr = hb + (y + j) * HSTR + xp;
                float xv[5];
                #pragma unroll
                for (int t = 0; t < 5; t++) xv[t] = pr[t];
                {   // ry = 0, ky = 8-2j
                    const int kyo = (8 - 2 * j) * 9;
                    #pragma unroll
                    for (int kx = 0; kx < 9; kx++) {
                        const int n = kx >> 1, rx = kx & 1;
                        #pragma unroll
                        for (int c = 0; c < 3; c++)
                            acc[c][rx] = fmaf(xv[4 - n], wb[c * 81 + kyo + kx], acc[c][rx]);
                    }
                }
                if (j >= 1) {   // ry = 1, ky = 9-2j
                    const int kyo = (9 - 2 * j) * 9;
                    #pragma unroll
                    for (int kx = 0; kx < 9; kx++) {
                        const int n = kx >> 1, rx = kx & 1;
                        #pragma unroll
                        for (int c = 0; c < 3; c++)
                            acc[c][2 + rx] = fmaf(xv[4 - n], wb[c * 81 + kyo + kx], acc[c][2 + rx]);
                    }
                }
            }
        }
        __syncthreads();
    }

    // ---------------- store 2x2 output block per thread ----------------
    float* op = out + (img * 3) * 4096 + (2 * y) * 64 + 2 * xp;
    #pragma unroll
    for (int c = 0; c < 3; c++) {
        *reinterpret_cast<float2*>(op + c * 4096)      = make_float2(acc[c][0], acc[c][1]);
        *reinterpret_cast<float2*>(op + c * 4096 + 64) = make_float2(acc[c][2], acc[c][3]);
    }
}

extern "C" void kernel_launch(void* const* d_in, const int* in_sizes, int n_in,
                              void* d_out, int out_size, void* d_ws, size_t ws_size,
                              hipStream_t stream) {
    (void)in_sizes; (void)n_in; (void)d_ws; (void)ws_size; (void)out_size;
    const float* x      = (const float*)d_in[0];
    const float* head_w = (const float*)d_in[1];
    const float* head_b = (const float*)d_in[2];
    const float* head_a = (const float*)d_in[3];
    const float* b0_w   = (const float*)d_in[4];
    const float* b0_b   = (const float*)d_in[5];
    const float* b0_a   = (const float*)d_in[6];
    const float* b1_w   = (const float*)d_in[7];
    const float* b1_b   = (const float*)d_in[8];
    const float* b2_w   = (const float*)d_in[9];
    const float* b2_b   = (const float*)d_in[10];
    const float* b3_w   = (const float*)d_in[11];
    const float* b3_b   = (const float*)d_in[12];
    const float* b4_w   = (const float*)d_in[13];
    const float* b4_b   = (const float*)d_in[14];
    const float* b5_a   = (const float*)d_in[15];
    const float* b6_w   = (const float*)d_in[16];
    const float* b6_b   = (const float*)d_in[17];
    const float* b6_a   = (const float*)d_in[18];
    const float* tail_w = (const float*)d_in[19];
    const float* tail_b = (const float*)d_in[20];
    float* out = (float*)d_out;

    hipFuncSetAttribute(reinterpret_cast<const void*>(fsrcnn_fused),
                        hipFuncAttributeMaxDynamicSharedMemorySize, LDS_BYTES);
    fsrcnn_fused<<<1024, TB, LDS_BYTES, stream>>>(
        x, head_w, head_b, head_a, b0_w, b0_b, b0_a,
        b1_w, b1_b, b2_w, b2_b, b3_w, b3_b, b4_w, b4_b, b5_a,
        b6_w, b6_b, b6_a, tail_w, tail_b, out);
}